// Round 8
// baseline (117.410 us; speedup 1.0000x reference)
//
#include <hip/hip_runtime.h>

typedef unsigned short u16;
typedef unsigned int   u32;
typedef __attribute__((ext_vector_type(8))) short bf16x8;
typedef __attribute__((ext_vector_type(4))) float f32x4;
typedef __attribute__((ext_vector_type(4))) u32   u32x4;
typedef __attribute__((ext_vector_type(2))) u32   u32x2;

#define MFMA(a,b,c) __builtin_amdgcn_mfma_f32_16x16x32_bf16(a,b,c,0,0,0)

// B=4, S=1024, E=1024, H=16, D=64; M = B*S = 4096.

__device__ __forceinline__ u32 cvtpk(float lo, float hi){
  u32 r; asm("v_cvt_pk_bf16_f32 %0, %1, %2" : "=v"(r) : "v"(lo), "v"(hi)); return r;
}
__device__ __forceinline__ u16 f2bf(float f){ return (u16)cvtpk(f,f); }  // RNE, 1 instr
__device__ __forceinline__ bf16x8 cvt8(f32x4 lo, f32x4 hi){
  u32x4 u;
  u.x = cvtpk(lo[0],lo[1]); u.y = cvtpk(lo[2],lo[3]);
  u.z = cvtpk(hi[0],hi[1]); u.w = cvtpk(hi[2],hi[3]);
  return *(bf16x8*)&u;
}

// XOR swizzle for [row][64 bf16] LDS tiles (128B rows). BYTE offset.
__device__ __forceinline__ int swz(int row, int col){
  return (((row<<6) + col)<<1) ^ ((row&7)<<4);
}

// async global->LDS, 16B/lane; LDS dest wave-uniform (HW adds lane*16)
__device__ __forceinline__ void gl16(const void* g, void* l){
  __builtin_amdgcn_global_load_lds(
      (const __attribute__((address_space(1))) u32*)g,
      (__attribute__((address_space(3))) u32*)l, 16, 0, 0);
}

// stage ROWSx64 bf16 tile via global_load_lds; source-side swizzle ^(row&7).
template<int ROWS>
__device__ __forceinline__ void stage_bf16(const u16* g, size_t ldg, char* lds, int wv, int lane){
  #pragma unroll
  for (int i=0;i<ROWS/32;++i){
    const int r0 = wv*(ROWS/4) + (i<<3);
    const int row = r0 + (lane>>3);
    const int c = ((lane&7) ^ (row&7)) << 3;
    gl16(g + (size_t)row*ldg + c, lds + (r0<<7));
  }
}

// reg-stage ROWSx64 f32 tile -> bf16 LDS (ldg = 1024 f32).
// Per instr: 8 consecutive rows x 128B contiguous -> full-line coalesced.
// LDS write swizzle matches swz(): byte ^ ((row&7)<<4).
template<int ROWS>
__device__ __forceinline__ void stage_cvt(const float* g, char* lds, int wv, int lane){
  constexpr int R  = ROWS/4;    // rows per wave
  constexpr int NI = ROWS/16;   // iters per lane
  constexpr int RI = R/8;       // row-subiters
  f32x4 tmp[NI];
  #pragma unroll
  for (int i=0;i<NI;++i){
    const int row = wv*R + (i%RI)*8 + (lane>>3);
    const int ch  = (lane&7) + 8*(i/RI);           // 16B (4-float) chunk, 0..15
    tmp[i] = *(const f32x4*)(g + (size_t)row*1024 + (ch<<2));
  }
  #pragma unroll
  for (int i=0;i<NI;++i){
    const int row = wv*R + (i%RI)*8 + (lane>>3);
    const int ch  = (lane&7) + 8*(i/RI);
    u32x2 w; w.x = cvtpk(tmp[i][0],tmp[i][1]); w.y = cvtpk(tmp[i][2],tmp[i][3]);
    *(u32x2*)(lds + (((row<<7) + (ch<<3)) ^ ((row&7)<<4))) = w;
  }
}

__device__ __forceinline__ bf16x8 frag_bf16(const char* lds, int row, int kcol){
  return *(const bf16x8*)(lds + swz(row,kcol));
}

// ---------------- weight fp32 -> bf16 (wq|wk|wo contiguous) ----------------
__global__ __launch_bounds__(256) void cvtw_k(const float* __restrict__ wq,
    const float* __restrict__ wk, const float* __restrict__ wo, u16* __restrict__ out)
{
  const size_t i8 = (((size_t)blockIdx.x<<8) + threadIdx.x) << 3;
  const float* src;
  if      (i8 <  1048576u) src = wq + i8;
  else if (i8 <  2097152u) src = wk + (i8 - 1048576u);
  else                     src = wo + (i8 - 2097152u);
  f32x4 lo = *(const f32x4*)src, hi = *(const f32x4*)(src+4);
  *(bf16x8*)(out + i8) = cvt8(lo, hi);
}

// ---------------- GEMM family: C = A @ B^T (+bias) ----------------
// V=0: A=f32 q/k (reg-staged->bf16 LDS), B=bf16 Wq/Wk gl_lds, BN=128, out bf16 [4096,1024]
// V=1: A=bf16 Wk gl_lds, B=f32 v (reg-staged), BN=64, bias[m], out bf16 vt [1024,4096]
// V=2: A=bf16 ctx, B=bf16 Wo (both gl_lds), BN=64, out f32 [4096,1024]
template<int V>
__global__ __launch_bounds__(256) void gemm_k(
    const float* __restrict__ Xf0, const float* __restrict__ Xf1,
    const u16* __restrict__ W0, const u16* __restrict__ W1,
    const float* __restrict__ b0, const float* __restrict__ b1,
    u16* __restrict__ o0, u16* __restrict__ o1, float* __restrict__ of)
{
  constexpr int BN = (V==0)?128:64;
  constexpr int NT = BN/32;            // n-frags per wave
  __shared__ __align__(16) char As[16384];     // 128x64 bf16
  __shared__ __align__(16) char Bs[BN*128];    // BNx64 bf16

  const float* Xa=nullptr;   // f32 reg-staged operand (V0: A, V1: B)
  const u16* Aa=nullptr; const u16* Bb=nullptr;
  const float* bias; u16* outb=nullptr;
  if (V==0){
    const int z = blockIdx.z;
    Xa = z?Xf1:Xf0; Bb = z?W1:W0; bias = z?b1:b0; outb = z?o1:o0;
  } else if (V==1){ Aa = W0; Xa = Xf0; bias = b0; outb = o0; }
  else            { Aa = W0; Bb = W1; bias = b0; }

  const int m0 = blockIdx.x<<7, n0 = blockIdx.y*BN;
  const int tid = threadIdx.x, lane = tid&63, wv = tid>>6;
  const int wm = wv>>1, wn = wv&1, l15 = lane&15, g4 = lane>>4;

  f32x4 acc[4][NT] = {};

  #pragma unroll 1
  for (int kt=0; kt<1024; kt+=64){
    __syncthreads();
    if (V==0){
      stage_cvt <128>(Xa + (size_t)m0*1024 + kt, As, wv, lane);
      stage_bf16<128>(Bb + (size_t)n0*1024 + kt, 1024, Bs, wv, lane);
    } else if (V==1){
      stage_bf16<128>(Aa + (size_t)m0*1024 + kt, 1024, As, wv, lane);
      stage_cvt <64> (Xa + (size_t)n0*1024 + kt, Bs, wv, lane);
    } else {
      stage_bf16<128>(Aa + (size_t)m0*1024 + kt, 1024, As, wv, lane);
      stage_bf16<BN> (Bb + (size_t)n0*1024 + kt, 1024, Bs, wv, lane);
    }
    __syncthreads();

    #pragma unroll
    for (int kb=0;kb<64;kb+=32){
      const int kcol = kb + (g4<<3);
      bf16x8 af[4], bf_[NT];
      #pragma unroll
      for (int t=0;t<4;++t)
        af[t] = frag_bf16(As, (wm<<6) + (t<<4) + l15, kcol);
      #pragma unroll
      for (int t=0;t<NT;++t)
        bf_[t] = frag_bf16(Bs, wn*(BN>>1) + (t<<4) + l15, kcol);
      __builtin_amdgcn_s_setprio(1);
      #pragma unroll
      for (int mt=0;mt<4;++mt)
        #pragma unroll
        for (int nt=0;nt<NT;++nt)
          acc[mt][nt] = MFMA(af[mt], bf_[nt], acc[mt][nt]);
      __builtin_amdgcn_s_setprio(0);
    }
  }

  f32x4 bmv[4];
  if (V==1){
    #pragma unroll
    for (int mt=0;mt<4;++mt)
      bmv[mt] = *(const f32x4*)(b0 + m0 + (wm<<6) + (mt<<4) + (g4<<2));
  }
  #pragma unroll
  for (int nt=0;nt<NT;++nt){
    const int col = n0 + wn*(BN>>1) + (nt<<4) + l15;
    const float bvn = (V==1) ? 0.f : bias[col];
    #pragma unroll
    for (int mt=0;mt<4;++mt){
      const int mb = m0 + (wm<<6) + (mt<<4) + (g4<<2);
      f32x4 a = acc[mt][nt];
      #pragma unroll
      for (int j=0;j<4;++j){
        const float val = a[j] + ((V==1) ? bmv[mt][j] : bvn);
        if      (V==2) of  [(size_t)(mb+j)*1024 + col] = val;
        else if (V==1) outb[(size_t)(mb+j)*4096 + col] = f2bf(val);
        else           outb[(size_t)(mb+j)*1024 + col] = f2bf(val);
      }
    }
  }
}

// ---------------- flash attention (proven structure; exp2-domain softmax) ----------------
// qp/kp bf16 [B*S,E]; vt bf16 [E,B*S]. ctx bf16 [B*S,E].
// Block: 128 q-rows x (h,b); 4 waves x 32 rows. KV tiles 64, dbuf.
__global__ __launch_bounds__(256) void attn_k(
    const u16* __restrict__ qp, const u16* __restrict__ kp, const u16* __restrict__ vt,
    const int* __restrict__ mask, u16* __restrict__ ctx)
{
  const int bid = blockIdx.x;
  const int wg  = (bid&7)*64 + (bid>>3);     // XCD-chunked (512 = 8*64, bijective)
  const int qt = wg&7, h = (wg>>3)&15, b = wg>>7;

  __shared__ __align__(16) u16 Qs[128*64];    // 16KB
  __shared__ __align__(16) u16 Ks[2][64*64];  // 16KB
  __shared__ __align__(16) u16 Vs[2][64*64];  // 16KB (rows=d, cols=key)
  __shared__ __align__(16) u16 Ps[4*32*64];   // 16KB per-wave P
  __shared__ __align__(16) float biasl[1024]; // 4KB (exp2-domain: 0 or -1e30)

  const int tid = threadIdx.x, lane = tid&63, wv = tid>>6;
  const int hc = h<<6;
  const float C2 = 0.18033688011112042f;      // 0.125 * log2(e)

  { // mask -> additive exp2-bias (v_exp_f32(-1.8e29) underflows to exact 0)
    const int4 mv = *(const int4*)(mask + (b<<10) + (tid<<2));
    float* bl = biasl + (tid<<2);
    bl[0] = mv.x ? 0.f : -1e30f;
    bl[1] = mv.y ? 0.f : -1e30f;
    bl[2] = mv.z ? 0.f : -1e30f;
    bl[3] = mv.w ? 0.f : -1e30f;
  }

  { // stage Q (128 x 64)
    const u16* Qg = qp + ((size_t)((b<<10) + (qt<<7)))*1024 + hc;
    #pragma unroll
    for (int i=0;i<4;++i){
      const int r0 = (wv<<5) + (i<<3);
      const int row = r0 + (lane>>3);
      const int c = ((lane&7) ^ (row&7)) << 3;
      gl16(Qg + (size_t)row*1024 + c, (char*)Qs + (r0<<7));
    }
  }

  const u16* Kg = kp + ((size_t)(b<<10))*1024 + hc;
  const u16* Vg = vt + ((size_t)hc)*4096 + (b<<10);

  auto stageKV = [&](int kt2, int bi){
    #pragma unroll
    for (int i=0;i<2;++i){
      const int r0 = (wv<<4) + (i<<3);
      const int row = r0 + (lane>>3);
      const int c = ((lane&7) ^ (row&7)) << 3;
      gl16(Kg + (size_t)((kt2<<6) + row)*1024 + c, (char*)Ks[bi] + (r0<<7));
      gl16(Vg + (size_t)row*4096 + (kt2<<6) + c,  (char*)Vs[bi] + (r0<<7));
    }
  };
  stageKV(0, 0);
  __syncthreads();

  f32x4 o[2][4] = {};
  float lr[2][4] = {};
  u16* Pw = Ps + (wv<<11);
  int cur = 0;

  #pragma unroll 1
  for (int kt=0; kt<16; ++kt){
    if (kt<15) stageKV(kt+1, cur^1);
    const char* Kc = (const char*)Ks[cur];
    const char* Vc = (const char*)Vs[cur];

    // S = Q K^T  (2 q-subtiles x 4 key-subtiles)
    f32x4 sc[2][4] = {};
    #pragma unroll
    for (int kb=0;kb<64;kb+=32){
      const int kcol = kb + ((lane>>4)<<3);
      bf16x8 kf[4];
      #pragma unroll
      for (int nt=0;nt<4;++nt) kf[nt] = frag_bf16(Kc, (nt<<4)+(lane&15), kcol);
      bf16x8 aq0 = frag_bf16((const char*)Qs, (wv<<5)+(lane&15), kcol);
      bf16x8 aq1 = frag_bf16((const char*)Qs, (wv<<5)+16+(lane&15), kcol);
      __builtin_amdgcn_s_setprio(1);
      #pragma unroll
      for (int nt=0;nt<4;++nt) sc[0][nt] = MFMA(aq0, kf[nt], sc[0][nt]);
      #pragma unroll
      for (int nt=0;nt<4;++nt) sc[1][nt] = MFMA(aq1, kf[nt], sc[1][nt]);
      __builtin_amdgcn_s_setprio(0);
    }

    // p = exp2(s*C2 + bias); masked -> exact 0. No max, no rescale.
    float bv4[4];
    #pragma unroll
    for (int nt=0;nt<4;++nt) bv4[nt] = biasl[(kt<<6)+(nt<<4)+(lane&15)];
    #pragma unroll
    for (int sub=0;sub<2;++sub)
      #pragma unroll
      for (int nt=0;nt<4;++nt){
        f32x4 s = sc[sub][nt];
        #pragma unroll
        for (int j=0;j<4;++j){
          const float p = __builtin_amdgcn_exp2f(fmaf(s[j], C2, bv4[nt]));
          lr[sub][j] += p;
          *(u16*)((char*)Pw + swz((sub<<4)+((lane>>4)<<2)+j, (nt<<4)+(lane&15))) = f2bf(p);
        }
      }
    asm volatile("s_waitcnt lgkmcnt(0)" ::: "memory");
    __builtin_amdgcn_sched_barrier(0);

    // O += P V
    #pragma unroll
    for (int kb=0;kb<64;kb+=32){
      const int kcol = kb + ((lane>>4)<<3);
      bf16x8 vf[4];
      #pragma unroll
      for (int nt=0;nt<4;++nt) vf[nt] = frag_bf16(Vc, (nt<<4)+(lane&15), kcol);
      bf16x8 pa0 = frag_bf16((const char*)Pw, (lane&15), kcol);
      bf16x8 pa1 = frag_bf16((const char*)Pw, 16+(lane&15), kcol);
      __builtin_amdgcn_s_setprio(1);
      #pragma unroll
      for (int nt=0;nt<4;++nt) o[0][nt] = MFMA(pa0, vf[nt], o[0][nt]);
      #pragma unroll
      for (int nt=0;nt<4;++nt) o[1][nt] = MFMA(pa1, vf[nt], o[1][nt]);
      __builtin_amdgcn_s_setprio(0);
    }
    __syncthreads();
    cur ^= 1;
  }

  // epilogue: deferred row-sum reduce (keys spread over lane&15), normalize, write
  #pragma unroll
  for (int sub=0;sub<2;++sub)
    #pragma unroll
    for (int j=0;j<4;++j){
      float s = lr[sub][j];
      s += __shfl_xor(s,1); s += __shfl_xor(s,2);
      s += __shfl_xor(s,4); s += __shfl_xor(s,8);
      const float inv = 1.f / fmaxf(s, 1e-30f);
      const int row = (qt<<7) + (wv<<5) + (sub<<4) + ((lane>>4)<<2) + j;
      u16* crow = ctx + ((size_t)((b<<10)+row))*1024 + hc;
      #pragma unroll
      for (int nt=0;nt<4;++nt)
        crow[(nt<<4)+(lane&15)] = f2bf(o[sub][nt][j]*inv);
    }
}

extern "C" void kernel_launch(void* const* d_in, const int* in_sizes, int n_in,
                              void* d_out, int out_size, void* d_ws, size_t ws_size,
                              hipStream_t stream) {
  const float* q    = (const float*)d_in[0];
  const float* k    = (const float*)d_in[1];
  const float* v    = (const float*)d_in[2];
  const int*   mask = (const int*)  d_in[3];
  const float* Wq   = (const float*)d_in[4];
  const float* bq   = (const float*)d_in[5];
  const float* Wk   = (const float*)d_in[6];
  const float* bk   = (const float*)d_in[7];
  const float* Wo   = (const float*)d_in[8];
  const float* bo   = (const float*)d_in[9];
  float* out = (float*)d_out;

  // ws: wqb 2M | wkb 2M | wob 2M | qp 8M | kp 8M | vt 8M | ctx 8M = 38 MiB
  char* ws = (char*)d_ws;
  u16* wqb  = (u16*)(ws);
  u16* wkb  = (u16*)(ws +  2097152);
  u16* wob  = (u16*)(ws +  4194304);
  u16* qp   = (u16*)(ws +  6291456);
  u16* kp   = (u16*)(ws + 14680064);
  u16* vtb  = (u16*)(ws + 23068672);
  u16* ctxb = (u16*)(ws + 31457280);

  dim3 blk(256);
  cvtw_k<<<1536, blk, 0, stream>>>(Wq, Wk, Wo, wqb);
  // q,k projections -> bf16 row-major
  gemm_k<0><<<dim3(32,8,2), blk, 0, stream>>>(q, k, wqb, wkb, bq, bk, qp, kp, nullptr);
  // v projection transposed: vt = Wk @ v^T + bk (reference uses Wk/bk for v)
  gemm_k<1><<<dim3(8,64), blk, 0, stream>>>(v, nullptr, wkb, nullptr, bk, nullptr,
                                            vtb, nullptr, nullptr);
  attn_k<<<512, blk, 0, stream>>>(qp, kp, vtb, mask, ctxb);
  gemm_k<2><<<dim3(32,16), blk, 0, stream>>>(nullptr, nullptr, ctxb, wob, bo, nullptr,
                                             nullptr, nullptr, out);
}

// Round 9
// 109.307 us; speedup vs baseline: 1.0741x; 1.0741x over previous
//
#include <hip/hip_runtime.h>

typedef unsigned short u16;
typedef unsigned int   u32;
typedef __attribute__((ext_vector_type(8))) short bf16x8;
typedef __attribute__((ext_vector_type(4))) float f32x4;
typedef __attribute__((ext_vector_type(4))) u32   u32x4;
typedef __attribute__((ext_vector_type(2))) u32   u32x2;

#define MFMA(a,b,c) __builtin_amdgcn_mfma_f32_16x16x32_bf16(a,b,c,0,0,0)

// B=4, S=1024, E=1024, H=16, D=64; M = B*S = 4096.

__device__ __forceinline__ u32 cvtpk(float lo, float hi){
  u32 r; asm("v_cvt_pk_bf16_f32 %0, %1, %2" : "=v"(r) : "v"(lo), "v"(hi)); return r;
}
__device__ __forceinline__ u16 f2bf(float f){ return (u16)cvtpk(f,f); }  // RNE, 1 instr
__device__ __forceinline__ bf16x8 cvt8(f32x4 lo, f32x4 hi){
  u32x4 u;
  u.x = cvtpk(lo[0],lo[1]); u.y = cvtpk(lo[2],lo[3]);
  u.z = cvtpk(hi[0],hi[1]); u.w = cvtpk(hi[2],hi[3]);
  return *(bf16x8*)&u;
}

// XOR swizzle for [row][64 bf16] LDS tiles (128B rows). BYTE offset.
__device__ __forceinline__ int swz(int row, int col){
  return (((row<<6) + col)<<1) ^ ((row&7)<<4);
}

// async global->LDS, 16B/lane; LDS dest wave-uniform (HW adds lane*16)
__device__ __forceinline__ void gl16(const void* g, void* l){
  __builtin_amdgcn_global_load_lds(
      (const __attribute__((address_space(1))) u32*)g,
      (__attribute__((address_space(3))) u32*)l, 16, 0, 0);
}

// stage ROWSx64 bf16 tile via global_load_lds; source-side swizzle ^(row&7).
template<int ROWS>
__device__ __forceinline__ void stage_bf16(const u16* g, size_t ldg, char* lds, int wv, int lane){
  #pragma unroll
  for (int i=0;i<ROWS/32;++i){
    const int r0 = wv*(ROWS/4) + (i<<3);
    const int row = r0 + (lane>>3);
    const int c = ((lane&7) ^ (row&7)) << 3;
    gl16(g + (size_t)row*ldg + c, lds + (r0<<7));
  }
}

// reg-staged f32->bf16 tile: load phase (issue early, hold in regs)
// lane covers (row = wbase + i*8 + lane>>3, c16 = lane&7); 32B f32 per slot.
template<int ROWS>
__device__ __forceinline__ void cvt_load(const float* g, f32x4* t, int wv, int lane){
  #pragma unroll
  for (int i=0;i<ROWS/32;++i){
    const int row = wv*(ROWS/4) + (i<<3) + (lane>>3);
    const float* s = g + (size_t)row*1024 + ((lane&7)<<3);
    t[2*i]   = *(const f32x4*)s;
    t[2*i+1] = *(const f32x4*)(s+4);
  }
}
// write phase (after compute): 1 b128 per slot; bank bits[4:2] = c16^row -> conflict-free
template<int ROWS>
__device__ __forceinline__ void cvt_write(const f32x4* t, char* lds, int wv, int lane){
  #pragma unroll
  for (int i=0;i<ROWS/32;++i){
    const int row = wv*(ROWS/4) + (i<<3) + (lane>>3);
    *(bf16x8*)(lds + swz(row, (lane&7)<<3)) = cvt8(t[2*i], t[2*i+1]);
  }
}

__device__ __forceinline__ bf16x8 frag_bf16(const char* lds, int row, int kcol){
  return *(const bf16x8*)(lds + swz(row,kcol));
}

// ---------------- weight fp32 -> bf16 (wq|wk|wo contiguous) ----------------
__global__ __launch_bounds__(256) void cvtw_k(const float* __restrict__ wq,
    const float* __restrict__ wk, const float* __restrict__ wo, u16* __restrict__ out)
{
  const size_t i8 = (((size_t)blockIdx.x<<8) + threadIdx.x) << 3;
  const float* src;
  if      (i8 <  1048576u) src = wq + i8;
  else if (i8 <  2097152u) src = wk + (i8 - 1048576u);
  else                     src = wo + (i8 - 2097152u);
  f32x4 lo = *(const f32x4*)src, hi = *(const f32x4*)(src+4);
  *(bf16x8*)(out + i8) = cvt8(lo, hi);
}

// ---------------- GEMM family: C = A @ B^T (+bias), 2-phase dbuf ----------------
// V=0: A=f32 q/k (reg-cvt), B=bf16 Wq/Wk gl_lds, BN=128, out bf16 [4096,1024]
// V=1: A=bf16 Wk gl_lds, B=f32 v (reg-cvt), BN=64, bias[m], out bf16 vt [1024,4096]
// V=2: A=bf16 ctx, B=bf16 Wo (both gl_lds), BN=64, out f32 [4096,1024]
template<int V>
__global__ __launch_bounds__(256,4) void gemm_k(
    const float* __restrict__ Xf0, const float* __restrict__ Xf1,
    const u16* __restrict__ W0, const u16* __restrict__ W1,
    const float* __restrict__ b0, const float* __restrict__ b1,
    u16* __restrict__ o0, u16* __restrict__ o1, float* __restrict__ of)
{
  constexpr int BN = (V==0)?128:64;
  constexpr int NT = BN/32;            // n-frags per wave
  constexpr bool AF = (V==0);          // A reg-cvt from f32
  constexpr bool BF = (V==1);          // B reg-cvt from f32
  __shared__ __align__(16) char As[2][16384];    // 128x64 bf16 dbuf
  __shared__ __align__(16) char Bs[2][BN*128];   // BNx64 bf16 dbuf

  const float* Xa=nullptr;   // f32 source (V0: A, V1: B)
  const u16* Aa=nullptr; const u16* Bb=nullptr;
  const float* bias; u16* outb=nullptr;
  if (V==0){
    const int z = blockIdx.z;
    Xa = z?Xf1:Xf0; Bb = z?W1:W0; bias = z?b1:b0; outb = z?o1:o0;
  } else if (V==1){ Aa = W0; Xa = Xf0; bias = b0; outb = o0; }
  else            { Aa = W0; Bb = W1; bias = b0; }

  const int m0 = blockIdx.x<<7, n0 = blockIdx.y*BN;
  const int tid = threadIdx.x, lane = tid&63, wv = tid>>6;
  const int wm = wv>>1, wn = wv&1, l15 = lane&15, g4 = lane>>4;

  f32x4 acc[4][NT] = {};
  f32x4 ta[8];   // V0 A-hold (32 VGPR)
  f32x4 tb[4];   // V1 B-hold (16 VGPR)

  // prologue: stage tile 0 into buf 0
  if (AF) cvt_load<128>(Xa + (size_t)m0*1024, ta, wv, lane);
  else    stage_bf16<128>(Aa + (size_t)m0*1024, 1024, As[0], wv, lane);
  if (BF) cvt_load<64>(Xa + (size_t)n0*1024, tb, wv, lane);
  else    stage_bf16<BN>(Bb + (size_t)n0*1024, 1024, Bs[0], wv, lane);
  if (AF) cvt_write<128>(ta, As[0], wv, lane);
  if (BF) cvt_write<64>(tb, Bs[0], wv, lane);
  __syncthreads();

  int cb = 0;
  #pragma unroll 1
  for (int kt=0; kt<1024; kt+=64){
    const bool more = (kt < 960);
    // issue next tile's loads BEFORE compute (latency hides under MFMA)
    if (more){
      if (AF) cvt_load<128>(Xa + (size_t)m0*1024 + kt+64, ta, wv, lane);
      else    stage_bf16<128>(Aa + (size_t)m0*1024 + kt+64, 1024, As[cb^1], wv, lane);
      if (BF) cvt_load<64>(Xa + (size_t)n0*1024 + kt+64, tb, wv, lane);
      else    stage_bf16<BN>(Bb + (size_t)n0*1024 + kt+64, 1024, Bs[cb^1], wv, lane);
    }
    // compute current buffer
    #pragma unroll
    for (int kb=0;kb<64;kb+=32){
      const int kcol = kb + (g4<<3);
      bf16x8 af[4], bf_[NT];
      #pragma unroll
      for (int t=0;t<4;++t)
        af[t] = frag_bf16(As[cb], (wm<<6) + (t<<4) + l15, kcol);
      #pragma unroll
      for (int t=0;t<NT;++t)
        bf_[t] = frag_bf16(Bs[cb], wn*(BN>>1) + (t<<4) + l15, kcol);
      __builtin_amdgcn_s_setprio(1);
      #pragma unroll
      for (int mt=0;mt<4;++mt)
        #pragma unroll
        for (int nt=0;nt<NT;++nt)
          acc[mt][nt] = MFMA(af[mt], bf_[nt], acc[mt][nt]);
      __builtin_amdgcn_s_setprio(0);
    }
    // land reg-staged writes into next buffer (auto-waits on its loads)
    if (more){
      if (AF) cvt_write<128>(ta, As[cb^1], wv, lane);
      if (BF) cvt_write<64>(tb, Bs[cb^1], wv, lane);
    }
    __syncthreads();   // drains vmcnt (gl16s of next tile) + lgkm; 1 barrier/kt
    cb ^= 1;
  }

  f32x4 bmv[4];
  if (V==1){
    #pragma unroll
    for (int mt=0;mt<4;++mt)
      bmv[mt] = *(const f32x4*)(b0 + m0 + (wm<<6) + (mt<<4) + (g4<<2));
  }
  #pragma unroll
  for (int nt=0;nt<NT;++nt){
    const int col = n0 + wn*(BN>>1) + (nt<<4) + l15;
    const float bvn = (V==1) ? 0.f : bias[col];
    #pragma unroll
    for (int mt=0;mt<4;++mt){
      const int mb = m0 + (wm<<6) + (mt<<4) + (g4<<2);
      f32x4 a = acc[mt][nt];
      #pragma unroll
      for (int j=0;j<4;++j){
        const float val = a[j] + ((V==1) ? bmv[mt][j] : bvn);
        if      (V==2) of  [(size_t)(mb+j)*1024 + col] = val;
        else if (V==1) outb[(size_t)(mb+j)*4096 + col] = f2bf(val);
        else           outb[(size_t)(mb+j)*1024 + col] = f2bf(val);
      }
    }
  }
}

// ---------------- flash attention (proven structure; exp2-domain softmax) ----------------
// qp/kp bf16 [B*S,E]; vt bf16 [E,B*S]. ctx bf16 [B*S,E].
// Block: 128 q-rows x (h,b); 4 waves x 32 rows. KV tiles 64, dbuf.
__global__ __launch_bounds__(256) void attn_k(
    const u16* __restrict__ qp, const u16* __restrict__ kp, const u16* __restrict__ vt,
    const int* __restrict__ mask, u16* __restrict__ ctx)
{
  const int bid = blockIdx.x;
  const int wg  = (bid&7)*64 + (bid>>3);     // XCD-chunked (512 = 8*64, bijective)
  const int qt = wg&7, h = (wg>>3)&15, b = wg>>7;

  __shared__ __align__(16) u16 Qs[128*64];    // 16KB
  __shared__ __align__(16) u16 Ks[2][64*64];  // 16KB
  __shared__ __align__(16) u16 Vs[2][64*64];  // 16KB (rows=d, cols=key)
  __shared__ __align__(16) u16 Ps[4*32*64];   // 16KB per-wave P
  __shared__ __align__(16) float biasl[1024]; // 4KB (exp2-domain: 0 or -1e30)

  const int tid = threadIdx.x, lane = tid&63, wv = tid>>6;
  const int hc = h<<6;
  const float C2 = 0.18033688011112042f;      // 0.125 * log2(e)

  { // mask -> additive exp2-bias (v_exp_f32(-1.8e29) underflows to exact 0)
    const int4 mv = *(const int4*)(mask + (b<<10) + (tid<<2));
    float* bl = biasl + (tid<<2);
    bl[0] = mv.x ? 0.f : -1e30f;
    bl[1] = mv.y ? 0.f : -1e30f;
    bl[2] = mv.z ? 0.f : -1e30f;
    bl[3] = mv.w ? 0.f : -1e30f;
  }

  { // stage Q (128 x 64)
    const u16* Qg = qp + ((size_t)((b<<10) + (qt<<7)))*1024 + hc;
    #pragma unroll
    for (int i=0;i<4;++i){
      const int r0 = (wv<<5) + (i<<3);
      const int row = r0 + (lane>>3);
      const int c = ((lane&7) ^ (row&7)) << 3;
      gl16(Qg + (size_t)row*1024 + c, (char*)Qs + (r0<<7));
    }
  }

  const u16* Kg = kp + ((size_t)(b<<10))*1024 + hc;
  const u16* Vg = vt + ((size_t)hc)*4096 + (b<<10);

  auto stageKV = [&](int kt2, int bi){
    #pragma unroll
    for (int i=0;i<2;++i){
      const int r0 = (wv<<4) + (i<<3);
      const int row = r0 + (lane>>3);
      const int c = ((lane&7) ^ (row&7)) << 3;
      gl16(Kg + (size_t)((kt2<<6) + row)*1024 + c, (char*)Ks[bi] + (r0<<7));
      gl16(Vg + (size_t)row*4096 + (kt2<<6) + c,  (char*)Vs[bi] + (r0<<7));
    }
  };
  stageKV(0, 0);
  __syncthreads();

  f32x4 o[2][4] = {};
  float lr[2][4] = {};
  u16* Pw = Ps + (wv<<11);
  int cur = 0;

  #pragma unroll 1
  for (int kt=0; kt<16; ++kt){
    if (kt<15) stageKV(kt+1, cur^1);
    const char* Kc = (const char*)Ks[cur];
    const char* Vc = (const char*)Vs[cur];

    // S = Q K^T  (2 q-subtiles x 4 key-subtiles)
    f32x4 sc[2][4] = {};
    #pragma unroll
    for (int kb=0;kb<64;kb+=32){
      const int kcol = kb + ((lane>>4)<<3);
      bf16x8 kf[4];
      #pragma unroll
      for (int nt=0;nt<4;++nt) kf[nt] = frag_bf16(Kc, (nt<<4)+(lane&15), kcol);
      bf16x8 aq0 = frag_bf16((const char*)Qs, (wv<<5)+(lane&15), kcol);
      bf16x8 aq1 = frag_bf16((const char*)Qs, (wv<<5)+16+(lane&15), kcol);
      __builtin_amdgcn_s_setprio(1);
      #pragma unroll
      for (int nt=0;nt<4;++nt) sc[0][nt] = MFMA(aq0, kf[nt], sc[0][nt]);
      #pragma unroll
      for (int nt=0;nt<4;++nt) sc[1][nt] = MFMA(aq1, kf[nt], sc[1][nt]);
      __builtin_amdgcn_s_setprio(0);
    }

    // p = exp2(s*C2 + bias); masked -> exact 0. No max, no rescale.
    float bv4[4];
    #pragma unroll
    for (int nt=0;nt<4;++nt) bv4[nt] = biasl[(kt<<6)+(nt<<4)+(lane&15)];
    #pragma unroll
    for (int sub=0;sub<2;++sub)
      #pragma unroll
      for (int nt=0;nt<4;++nt){
        f32x4 s = sc[sub][nt];
        #pragma unroll
        for (int j=0;j<4;++j){
          const float p = __builtin_amdgcn_exp2f(fmaf(s[j], C2, bv4[nt]));
          lr[sub][j] += p;
          *(u16*)((char*)Pw + swz((sub<<4)+((lane>>4)<<2)+j, (nt<<4)+(lane&15))) = f2bf(p);
        }
      }
    asm volatile("s_waitcnt lgkmcnt(0)" ::: "memory");
    __builtin_amdgcn_sched_barrier(0);

    // O += P V
    #pragma unroll
    for (int kb=0;kb<64;kb+=32){
      const int kcol = kb + ((lane>>4)<<3);
      bf16x8 vf[4];
      #pragma unroll
      for (int nt=0;nt<4;++nt) vf[nt] = frag_bf16(Vc, (nt<<4)+(lane&15), kcol);
      bf16x8 pa0 = frag_bf16((const char*)Pw, (lane&15), kcol);
      bf16x8 pa1 = frag_bf16((const char*)Pw, 16+(lane&15), kcol);
      __builtin_amdgcn_s_setprio(1);
      #pragma unroll
      for (int nt=0;nt<4;++nt) o[0][nt] = MFMA(pa0, vf[nt], o[0][nt]);
      #pragma unroll
      for (int nt=0;nt<4;++nt) o[1][nt] = MFMA(pa1, vf[nt], o[1][nt]);
      __builtin_amdgcn_s_setprio(0);
    }
    __syncthreads();
    cur ^= 1;
  }

  // epilogue: deferred row-sum reduce (keys spread over lane&15), normalize, write
  #pragma unroll
  for (int sub=0;sub<2;++sub)
    #pragma unroll
    for (int j=0;j<4;++j){
      float s = lr[sub][j];
      s += __shfl_xor(s,1); s += __shfl_xor(s,2);
      s += __shfl_xor(s,4); s += __shfl_xor(s,8);
      const float inv = 1.f / fmaxf(s, 1e-30f);
      const int row = (qt<<7) + (wv<<5) + (sub<<4) + ((lane>>4)<<2) + j;
      u16* crow = ctx + ((size_t)((b<<10)+row))*1024 + hc;
      #pragma unroll
      for (int nt=0;nt<4;++nt)
        crow[(nt<<4)+(lane&15)] = f2bf(o[sub][nt][j]*inv);
    }
}

extern "C" void kernel_launch(void* const* d_in, const int* in_sizes, int n_in,
                              void* d_out, int out_size, void* d_ws, size_t ws_size,
                              hipStream_t stream) {
  const float* q    = (const float*)d_in[0];
  const float* k    = (const float*)d_in[1];
  const float* v    = (const float*)d_in[2];
  const int*   mask = (const int*)  d_in[3];
  const float* Wq   = (const float*)d_in[4];
  const float* bq   = (const float*)d_in[5];
  const float* Wk   = (const float*)d_in[6];
  const float* bk   = (const float*)d_in[7];
  const float* Wo   = (const float*)d_in[8];
  const float* bo   = (const float*)d_in[9];
  float* out = (float*)d_out;

  // ws: wqb 2M | wkb 2M | wob 2M | qp 8M | kp 8M | vt 8M | ctx 8M = 38 MiB
  char* ws = (char*)d_ws;
  u16* wqb  = (u16*)(ws);
  u16* wkb  = (u16*)(ws +  2097152);
  u16* wob  = (u16*)(ws +  4194304);
  u16* qp   = (u16*)(ws +  6291456);
  u16* kp   = (u16*)(ws + 14680064);
  u16* vtb  = (u16*)(ws + 23068672);
  u16* ctxb = (u16*)(ws + 31457280);

  dim3 blk(256);
  cvtw_k<<<1536, blk, 0, stream>>>(Wq, Wk, Wo, wqb);
  // q,k projections -> bf16 row-major
  gemm_k<0><<<dim3(32,8,2), blk, 0, stream>>>(q, k, wqb, wkb, bq, bk, qp, kp, nullptr);
  // v projection transposed: vt = Wk @ v^T + bk (reference uses Wk/bk for v)
  gemm_k<1><<<dim3(8,64), blk, 0, stream>>>(v, nullptr, wkb, nullptr, bk, nullptr,
                                            vtb, nullptr, nullptr);
  attn_k<<<512, blk, 0, stream>>>(qp, kp, vtb, mask, ctxb);
  gemm_k<2><<<dim3(32,16), blk, 0, stream>>>(nullptr, nullptr, ctxb, wob, bo, nullptr,
                                             nullptr, nullptr, out);
}